// Round 4
// baseline (220.351 us; speedup 1.0000x reference)
//
#include <hip/hip_runtime.h>
#include <stdint.h>

typedef __attribute__((ext_vector_type(8))) short short8;
typedef __attribute__((ext_vector_type(4))) float f32x4;
typedef __attribute__((ext_vector_type(4))) uint32_t u32x4;

#if __has_builtin(__builtin_amdgcn_exp2f)
#define EXP2(x) __builtin_amdgcn_exp2f(x)
#else
#define EXP2(x) exp2f(x)
#endif

__device__ __forceinline__ short f2bf(float f){
  uint32_t u = __builtin_bit_cast(uint32_t, f);
  uint32_t r = (u + 0x7fffu + ((u >> 16) & 1u)) >> 16;   // RTNE
  return (short)r;
}
// RTNE pack of two f32 -> one u32 (lo in low half) — software, unbiased
__device__ __forceinline__ uint32_t pk2(float lo, float hi){
  return ((uint32_t)(uint16_t)f2bf(hi) << 16) | (uint16_t)f2bf(lo);
}
__device__ __forceinline__ void gload16(const void* g, void* l){
  __builtin_amdgcn_global_load_lds((const __attribute__((address_space(1))) void*)g,
                                   (__attribute__((address_space(3))) void*)l, 16, 0, 0);
}

// ---------------- NT GEMM: C[M=4096,N=1024] = A[M,K]·Bw[N,K]^T + bias ----------------
// A: fp32 (AF32, on-the-fly RTNE cvt) or bf16 (gload_lds). B: always fp32, cvt on stage.
// MODE 0: bf16 head-scatter out. MODE 1: f32 linear out.
template<int MODE, bool AF32>
__global__ __launch_bounds__(256) void gemm_nt(const void* __restrict__ Ap, const float* __restrict__ Bw,
    const float* __restrict__ bias, void* __restrict__ Cout){
  const int K = 1024;
  int i = blockIdx.y*gridDim.x + blockIdx.x;   // 512 wgs
  int L = (i & 7)*64 + (i >> 3);               // XCD-contiguous chunks
  int by = L >> 4, bx = L & 15;
  int m0 = by*128, n0 = bx*64;
  __shared__ short Al[128*32];
  __shared__ short Bl[64*32];
  int tid = threadIdx.x;
  int w = tid >> 6, lane = tid & 63, lr = lane & 15, lg = lane >> 4;
  int wr = w >> 1, wc = w & 1;
  f32x4 acc[4][2] = {};
  // A staging (fp32 path): 16 floats/thread
  int ar = tid >> 1, akh = (tid & 1)*16;
  const float* Agf = (const float*)Ap + (size_t)(m0 + ar)*K + akh;
  int aw0 = ar*64 + ((akh*2)      ^ ((ar & 3) << 4));
  int aw1 = ar*64 + ((akh*2 + 16) ^ ((ar & 3) << 4));
  // A staging (bf16 path): gload_lds linear
  int sr = tid >> 2, sc = (tid & 3)*8;
  const short* Agh = (const short*)Ap + (size_t)(m0 + sr)*K + sc;
  char* Alb = (char*)Al + tid*16;
  // B staging: 8 floats/thread
  int br = tid >> 2, bkh = (tid & 3)*8;
  const float* Bgf = Bw + (size_t)(n0 + br)*K + bkh;
  int bw0 = br*64 + ((bkh*2) ^ ((br & 3) << 4));

  for (int k0 = 0; k0 < K; k0 += 32){
    if (AF32){
      float4 f0 = *(const float4*)(Agf + k0);
      float4 f1 = *(const float4*)(Agf + k0 + 4);
      float4 f2 = *(const float4*)(Agf + k0 + 8);
      float4 f3 = *(const float4*)(Agf + k0 + 12);
      u32x4 u0 = { pk2(f0.x,f0.y), pk2(f0.z,f0.w), pk2(f1.x,f1.y), pk2(f1.z,f1.w) };
      u32x4 u1 = { pk2(f2.x,f2.y), pk2(f2.z,f2.w), pk2(f3.x,f3.y), pk2(f3.z,f3.w) };
      *(u32x4*)((char*)Al + aw0) = u0;
      *(u32x4*)((char*)Al + aw1) = u1;
    } else {
      gload16(Agh + k0,                Alb);
      gload16(Agh + k0 + 64*(size_t)K, Alb + 4096);
    }
    {
      float4 g0 = *(const float4*)(Bgf + k0);
      float4 g1 = *(const float4*)(Bgf + k0 + 4);
      u32x4 ub = { pk2(g0.x,g0.y), pk2(g0.z,g0.w), pk2(g1.x,g1.y), pk2(g1.z,g1.w) };
      *(u32x4*)((char*)Bl + bw0) = ub;
    }
    __syncthreads();
    short8 av[4], bv[2];
#pragma unroll
    for (int mi=0; mi<4; ++mi){
      int row = wr*64 + mi*16 + lr;
      int ax = AF32 ? ((row & 3) << 4) : 0;
      av[mi] = *(const short8*)((char*)Al + row*64 + ((lg*16) ^ ax));
    }
#pragma unroll
    for (int ni=0; ni<2; ++ni){
      int rowb = wc*32 + ni*16 + lr;
      bv[ni] = *(const short8*)((char*)Bl + rowb*64 + ((lg*16) ^ ((rowb & 3) << 4)));
    }
#pragma unroll
    for (int mi=0; mi<4; ++mi)
#pragma unroll
      for (int ni=0; ni<2; ++ni)
        acc[mi][ni] = __builtin_amdgcn_mfma_f32_16x16x32_bf16(av[mi], bv[ni], acc[mi][ni], 0, 0, 0);
    __syncthreads();
  }
#pragma unroll
  for (int ni=0; ni<2; ++ni){
    int col = n0 + wc*32 + ni*16 + lr;
    float bb = bias[col];
#pragma unroll
    for (int mi=0; mi<4; ++mi){
#pragma unroll
      for (int i2=0; i2<4; ++i2){
        int row = m0 + wr*64 + mi*16 + lg*4 + i2;
        float val = acc[mi][ni][i2] + bb;
        if (MODE == 0){
          int b = row >> 11, s = row & 2047, h = col >> 6, d = col & 63;
          ((short*)Cout)[(((size_t)(b*16 + h))*2048 + s)*64 + d] = f2bf(val);
        } else {
          ((float*)Cout)[(size_t)row*1024 + col] = val;
        }
      }
    }
  }
}

// ---------------- flash attention (K direct from global, 2-tile ILP) ----------------
__global__ __launch_bounds__(256) void attn_fwd(const short* __restrict__ Qh, const short* __restrict__ Kh,
    const short* __restrict__ Vh, short* __restrict__ AO){
  const int S = 2048;
  int i = blockIdx.y*gridDim.x + blockIdx.x;   // 512 wgs
  int L = (i & 7)*64 + (i >> 3);
  int bh = L >> 4, qt = L & 15;
  __shared__ short Vt[2][64*72];     // pair of V^T tiles, col-swizzled
  __shared__ short Pl[4][2][32*72];  // per-wave double P
  int tid = threadIdx.x, w = tid >> 6, lane = tid & 63, lr = lane & 15, lg = lane >> 4;
  const short* Qb = Qh + (size_t)bh*S*64;
  const short* Kb = Kh + (size_t)bh*S*64;
  const short* Vb = Vh + (size_t)bh*S*64;
  int q0 = qt*128 + w*32;
  short8 aq[2][2];
#pragma unroll
  for (int m=0; m<2; ++m)
#pragma unroll
    for (int h=0; h<2; ++h)
      aq[m][h] = *(const short8*)&Qb[(size_t)(q0 + m*16 + lr)*64 + h*32 + lg*8];
  f32x4 o[2][4] = {};
  float lsum[2] = {0.f, 0.f};
  const float C = 0.18033688011112042f;   // log2(e)/8
  // V staging addressing
  int vr = w*8 + (lane >> 3);
  int d0 = (lane & 7)*8;
  int c0 = vr ^ d0, c1 = (vr + 32) ^ d0;
  // prologue: stage V pair 0
  {
    short8 a0 = *(const short8*)&Vb[(size_t)vr*64 + d0];
    short8 a1 = *(const short8*)&Vb[(size_t)(vr + 32)*64 + d0];
    short8 b0 = *(const short8*)&Vb[(size_t)(64 + vr)*64 + d0];
    short8 b1 = *(const short8*)&Vb[(size_t)(64 + vr + 32)*64 + d0];
#pragma unroll
    for (int j=0; j<8; ++j){
      Vt[0][(d0 + j)*72 + c0] = a0[j]; Vt[0][(d0 + j)*72 + c1] = a1[j];
      Vt[1][(d0 + j)*72 + c0] = b0[j]; Vt[1][(d0 + j)*72 + c1] = b1[j];
    }
  }
  __syncthreads();

  for (int t2 = 0; t2 < 16; ++t2){
    short8 nv[2][2];
    bool pre = (t2 < 15);
    if (pre){
#pragma unroll
      for (int u=0; u<2; ++u){
        const short* Vn = Vb + (size_t)(2*t2 + 2 + u)*4096;
        nv[u][0] = *(const short8*)&Vn[(size_t)vr*64 + d0];
        nv[u][1] = *(const short8*)&Vn[(size_t)(vr + 32)*64 + d0];
      }
    }
    // QK^T + exp + pack for both sub-tiles (independent chains)
#pragma unroll
    for (int u=0; u<2; ++u){
      const short* Kt = Kb + (size_t)(2*t2 + u)*4096;
      short* Pw = &Pl[w][u][0];
#pragma unroll
      for (int nf=0; nf<4; ++nf){
        short8 ak0 = *(const short8*)&Kt[(nf*16 + lr)*64 + lg*8];
        short8 ak1 = *(const short8*)&Kt[(nf*16 + lr)*64 + 32 + lg*8];
#pragma unroll
        for (int m=0; m<2; ++m){
          f32x4 z = {};
          z = __builtin_amdgcn_mfma_f32_16x16x32_bf16(ak0, aq[m][0], z, 0, 0, 0);
          z = __builtin_amdgcn_mfma_f32_16x16x32_bf16(ak1, aq[m][1], z, 0, 0, 0);
          float p0 = EXP2(z[0]*C), p1 = EXP2(z[1]*C);
          float p2 = EXP2(z[2]*C), p3 = EXP2(z[3]*C);
          lsum[m] += (p0 + p1) + (p2 + p3);
          uint2 pw; pw.x = pk2(p0, p1); pw.y = pk2(p2, p3);
          *(uint2*)&Pw[(m*16 + lr)*72 + nf*16 + (lg << 2)] = pw;
        }
      }
    }
    // PV for both sub-tiles
#pragma unroll
    for (int u=0; u<2; ++u){
      short* Pw = &Pl[w][u][0];
      short8 pa[2][2];
#pragma unroll
      for (int m=0; m<2; ++m)
#pragma unroll
        for (int c=0; c<2; ++c)
          pa[m][c] = *(const short8*)&Pw[(m*16 + lr)*72 + c*32 + (lg << 3)];
      const short* Vbuf = &Vt[u][0];
#pragma unroll
      for (int df=0; df<4; ++df){
        int h = (df*2 + (lr >> 3)) & 7;
        int rowv = (df*16 + lr)*72;
        short8 vb0 = *(const short8*)&Vbuf[rowv + ((lg ^ h) << 3)];
        short8 vb1 = *(const short8*)&Vbuf[rowv + (((lg + 4) ^ h) << 3)];
#pragma unroll
        for (int m=0; m<2; ++m){
          o[m][df] = __builtin_amdgcn_mfma_f32_16x16x32_bf16(pa[m][0], vb0, o[m][df], 0, 0, 0);
          o[m][df] = __builtin_amdgcn_mfma_f32_16x16x32_bf16(pa[m][1], vb1, o[m][df], 0, 0, 0);
        }
      }
    }
    if (pre){
      __syncthreads();
#pragma unroll
      for (int u=0; u<2; ++u)
#pragma unroll
        for (int j=0; j<8; ++j){
          Vt[u][(d0 + j)*72 + c0] = nv[u][0][j];
          Vt[u][(d0 + j)*72 + c1] = nv[u][1][j];
        }
      __syncthreads();
    }
  }
  // epilogue
  lsum[0] += __shfl_xor(lsum[0], 16); lsum[0] += __shfl_xor(lsum[0], 32);
  lsum[1] += __shfl_xor(lsum[1], 16); lsum[1] += __shfl_xor(lsum[1], 32);
  int b = bh >> 4, hh = bh & 15;
#pragma unroll
  for (int m=0; m<2; ++m){
    float rinv[4];
#pragma unroll
    for (int i2=0; i2<4; ++i2) rinv[i2] = 1.0f / __shfl(lsum[m], (lg << 2) + i2);
#pragma unroll
    for (int df=0; df<4; ++df)
#pragma unroll
      for (int i2=0; i2<4; ++i2){
        int row = q0 + m*16 + lg*4 + i2;
        int col = df*16 + lr;
        AO[((size_t)(b*2048 + row))*1024 + hh*64 + col] = f2bf(o[m][df][i2] * rinv[i2]);
      }
  }
}

extern "C" void kernel_launch(void* const* d_in, const int* in_sizes, int n_in,
                              void* d_out, int out_size, void* d_ws, size_t ws_size,
                              hipStream_t stream){
  const float* q  = (const float*)d_in[0];
  const float* k  = (const float*)d_in[1];
  const float* v  = (const float*)d_in[2];
  const float* Wq = (const float*)d_in[3];
  const float* bq = (const float*)d_in[4];
  const float* Wk = (const float*)d_in[5];
  const float* bk = (const float*)d_in[6];
  const float* Wv = (const float*)d_in[7];
  const float* bv = (const float*)d_in[8];
  const float* Wo = (const float*)d_in[9];
  const float* bo = (const float*)d_in[10];

  const size_t SQ = 4096ull*1024ull;
  short* ws = (short*)d_ws;
  short* Qh = ws;           // [B,H,S,D] bf16
  short* Kh = ws + SQ;
  short* Vh = ws + 2*SQ;
  short* AO = ws + 3*SQ;    // [B,S,E] bf16

  gemm_nt<0,true ><<<dim3(16, 32), 256, 0, stream>>>((const void*)q, Wq, bq, Qh);
  gemm_nt<0,true ><<<dim3(16, 32), 256, 0, stream>>>((const void*)k, Wk, bk, Kh);
  gemm_nt<0,true ><<<dim3(16, 32), 256, 0, stream>>>((const void*)v, Wv, bv, Vh);
  attn_fwd<<<dim3(16, 32), 256, 0, stream>>>(Qh, Kh, Vh, AO);
  gemm_nt<1,false><<<dim3(16, 32), 256, 0, stream>>>((const void*)AO, Wo, bo, d_out);
}

// Round 5
// 160.608 us; speedup vs baseline: 1.3720x; 1.3720x over previous
//
#include <hip/hip_runtime.h>
#include <stdint.h>

typedef __attribute__((ext_vector_type(8))) short short8;
typedef __attribute__((ext_vector_type(4))) float f32x4;

#if __has_builtin(__builtin_amdgcn_exp2f)
#define EXP2(x) __builtin_amdgcn_exp2f(x)
#else
#define EXP2(x) exp2f(x)
#endif

__device__ __forceinline__ short f2bf(float f){
  uint32_t u = __builtin_bit_cast(uint32_t, f);
  uint32_t r = (u + 0x7fffu + ((u >> 16) & 1u)) >> 16;   // RTNE
  return (short)r;
}
__device__ __forceinline__ uint32_t pk2(float lo, float hi){
  return ((uint32_t)(uint16_t)f2bf(hi) << 16) | (uint16_t)f2bf(lo);
}
__device__ __forceinline__ void gload16(const void* g, void* l){
  __builtin_amdgcn_global_load_lds((const __attribute__((address_space(1))) void*)g,
                                   (__attribute__((address_space(3))) void*)l, 16, 0, 0);
}

// ---------------- fp32 -> bf16 conversion of q,k,v,Wq,Wk,Wv,Wo ----------------
__global__ __launch_bounds__(256) void cvt_all(
    const float* __restrict__ q, const float* __restrict__ k, const float* __restrict__ v,
    const float* __restrict__ wq, const float* __restrict__ wk, const float* __restrict__ wv,
    const float* __restrict__ wo, short* __restrict__ dst){
  const size_t SQ = 4096ull*1024ull, NW = 1024ull*1024ull;
  size_t e = (size_t)(blockIdx.x*256u + threadIdx.x)*8ull;
  const float* src; size_t rel;
  if (e < 3*SQ){ size_t which = e / SQ; src = which==0?q:(which==1?k:v); rel = e - which*SQ; }
  else { size_t e2 = e - 3*SQ; size_t which = e2 / NW;
         src = which==0?wq:(which==1?wk:(which==2?wv:wo)); rel = e2 - which*NW; }
  float4 a = *(const float4*)(src + rel);
  float4 b = *(const float4*)(src + rel + 4);
  short8 r;
  r[0]=f2bf(a.x); r[1]=f2bf(a.y); r[2]=f2bf(a.z); r[3]=f2bf(a.w);
  r[4]=f2bf(b.x); r[5]=f2bf(b.y); r[6]=f2bf(b.z); r[7]=f2bf(b.w);
  *(short8*)(dst + e) = r;
}

// ---------------- NT GEMM: C[M=4096,N=1024] = A[M,K]·Bw[N,K]^T + bias ----------------
// 128x64 tile, 512 blocks. MODE 0: bf16 head-scatter out. MODE 1: f32 linear out.
template<int MODE>
__global__ __launch_bounds__(256) void gemm_nt(const short* __restrict__ A, const short* __restrict__ Bw,
    const float* __restrict__ bias, void* __restrict__ Cout){
  const int K = 1024;
  int i = blockIdx.y*gridDim.x + blockIdx.x;   // 512 wgs
  int L = (i & 7)*64 + (i >> 3);               // XCD-contiguous chunks
  int by = L >> 4, bx = L & 15;
  int m0 = by*128, n0 = bx*64;
  __shared__ short Al[128*32];
  __shared__ short Bl[64*32];
  int tid = threadIdx.x;
  int w = tid >> 6, lane = tid & 63, lr = lane & 15, lg = lane >> 4;
  int wr = w >> 1, wc = w & 1;
  f32x4 acc[4][2] = {};
  int sr = tid >> 2, sc = (tid & 3)*8;
  const short* Ag = A  + (size_t)(m0 + sr)*K + sc;
  const short* Bg = Bw + (size_t)(n0 + (sr & 63))*K + sc;
  char* Alb = (char*)Al + tid*16;
  char* Blb = (char*)Bl + tid*16;
  for (int k0 = 0; k0 < K; k0 += 32){
    gload16(Ag + k0,                Alb);
    gload16(Ag + k0 + 64*(size_t)K, Alb + 4096);
    gload16(Bg + k0, Blb);
    __syncthreads();
    short8 av[4], bv[2];
#pragma unroll
    for (int mi=0; mi<4; ++mi) av[mi] = *(const short8*)&Al[(wr*64 + mi*16 + lr)*32 + lg*8];
#pragma unroll
    for (int ni=0; ni<2; ++ni) bv[ni] = *(const short8*)&Bl[(wc*32 + ni*16 + lr)*32 + lg*8];
#pragma unroll
    for (int mi=0; mi<4; ++mi)
#pragma unroll
      for (int ni=0; ni<2; ++ni)
        acc[mi][ni] = __builtin_amdgcn_mfma_f32_16x16x32_bf16(av[mi], bv[ni], acc[mi][ni], 0, 0, 0);
    __syncthreads();
  }
#pragma unroll
  for (int ni=0; ni<2; ++ni){
    int col = n0 + wc*32 + ni*16 + lr;
    float bb = bias[col];
#pragma unroll
    for (int mi=0; mi<4; ++mi){
#pragma unroll
      for (int i2=0; i2<4; ++i2){
        int row = m0 + wr*64 + mi*16 + lg*4 + i2;
        float val = acc[mi][ni][i2] + bb;
        if (MODE == 0){
          int b = row >> 11, s = row & 2047, h = col >> 6, d = col & 63;
          ((short*)Cout)[(((size_t)(b*16 + h))*2048 + s)*64 + d] = f2bf(val);
        } else {
          ((float*)Cout)[(size_t)row*1024 + col] = val;
        }
      }
    }
  }
}

// ---------------- flash attention (swapped QK^T, permuted K-rows -> register P) ----------------
// K-row permutation: iteration nf covers K rows R = 32*(nf>>1) + 8*(lr>>2) + 4*(nf&1) + (lr&3).
// => lane(lg) accumulates scores for k = 32c + 8lg + 4*(nf&1) + i2, which IS the PV A-fragment
// set: P stays entirely in registers (no LDS roundtrip, no cross-lane ops).
__global__ __launch_bounds__(256) void attn_fwd(const short* __restrict__ Qh, const short* __restrict__ Kh,
    const short* __restrict__ Vh, short* __restrict__ AO){
  const int S = 2048;
  int i = blockIdx.y*gridDim.x + blockIdx.x;   // 512 wgs
  int L = (i & 7)*64 + (i >> 3);
  int bh = L >> 4, qt = L & 15;
  __shared__ short Kl[2][64*64];     // dbuf K; read-slot swizzle s(r)=(r&3)|((r>>3&1)<<2), source-side
  __shared__ short Vt[2][64*72];     // dbuf V^T[d][k], col swizzle k ^ (d&56)
  int tid = threadIdx.x, w = tid >> 6, lane = tid & 63, lr = lane & 15, lg = lane >> 4;
  const short* Qb = Qh + (size_t)bh*S*64;
  const short* Kb = Kh + (size_t)bh*S*64;
  const short* Vb = Vh + (size_t)bh*S*64;
  int q0 = qt*128 + w*32;
  short8 aq[2][2];
#pragma unroll
  for (int m=0; m<2; ++m)
#pragma unroll
    for (int h=0; h<2; ++h)
      aq[m][h] = *(const short8*)&Qb[(size_t)(q0 + m*16 + lr)*64 + h*32 + lg*8];
  f32x4 o[2][4] = {};
  float lsum[2] = {0.f, 0.f};
  const float C = 0.18033688011112042f;   // log2(e)/8
  // K staging: LDS dest linear (tid*16); source column pre-swizzled by s(row)
  int koff = tid*16;
  int kr = tid >> 3, kc = tid & 7;
  int ksw = (kr & 3) | (((kr >> 3) & 1) << 2);
  int ksrc = kr*64 + ((kc ^ ksw) << 3);        // elem offset (rows 0-31; +2048 covers 32-63, same swizzle)
  // K read addressing (hoisted)
  int Rbase = 8*(lr >> 2) + (lr & 3);
  int sR = (lr & 3) | (((lr >> 2) & 1) << 2);
  int slot0 = (lg ^ sR) << 3, slot1 = ((lg + 4) ^ sR) << 3;
  // V staging addressing
  int vr = w*8 + (lane >> 3);
  int d0 = (lane & 7)*8;
  int c0 = vr ^ d0, c1 = (vr + 32) ^ d0;
  // ---- prologue: stage tile 0 ----
  gload16(Kb + ksrc,        (char*)&Kl[0][0] + koff);
  gload16(Kb + ksrc + 2048, (char*)&Kl[0][0] + koff + 4096);
  {
    short8 v0 = *(const short8*)&Vb[(size_t)vr*64 + d0];
    short8 v1 = *(const short8*)&Vb[(size_t)(vr + 32)*64 + d0];
#pragma unroll
    for (int j=0; j<8; ++j){ Vt[0][(d0 + j)*72 + c0] = v0[j]; Vt[0][(d0 + j)*72 + c1] = v1[j]; }
  }
  __syncthreads();

  for (int t = 0; t < 32; ++t){
    int buf = t & 1, nbuf = buf ^ 1;
    short8 nv0, nv1;
    bool pre = (t + 1 < 32);
    if (pre){
      const short* Kt = Kb + (size_t)(t + 1)*4096;
      gload16(Kt + ksrc,        (char*)&Kl[nbuf][0] + koff);
      gload16(Kt + ksrc + 2048, (char*)&Kl[nbuf][0] + koff + 4096);
      nv0 = *(const short8*)&Vb[(size_t)((t + 1)*64 + vr)*64 + d0];
      nv1 = *(const short8*)&Vb[(size_t)((t + 1)*64 + vr + 32)*64 + d0];
    }
    // QK^T (swapped, permuted K-rows) + exp; P accumulates directly into A-fragment registers
    const short* Kbuf = &Kl[buf][0];
    uint32_t Wp[2][2][2][2];   // [m][c][nf0][s] — all indices compile-time after unroll
#pragma unroll
    for (int nf=0; nf<4; ++nf){
      int R = Rbase + (nf & 1)*4 + (nf >> 1)*32;
      short8 ak0 = *(const short8*)&Kbuf[R*64 + slot0];
      short8 ak1 = *(const short8*)&Kbuf[R*64 + slot1];
#pragma unroll
      for (int m=0; m<2; ++m){
        f32x4 z = {};
        z = __builtin_amdgcn_mfma_f32_16x16x32_bf16(ak0, aq[m][0], z, 0, 0, 0);
        z = __builtin_amdgcn_mfma_f32_16x16x32_bf16(ak1, aq[m][1], z, 0, 0, 0);
        float p0 = EXP2(z[0]*C), p1 = EXP2(z[1]*C);
        float p2 = EXP2(z[2]*C), p3 = EXP2(z[3]*C);
        lsum[m] += (p0 + p1) + (p2 + p3);
        Wp[m][nf >> 1][nf & 1][0] = pk2(p0, p1);
        Wp[m][nf >> 1][nf & 1][1] = pk2(p2, p3);
      }
    }
    short8 pa[2][2];
#pragma unroll
    for (int m=0; m<2; ++m)
#pragma unroll
      for (int c=0; c<2; ++c){
        union { uint32_t u[4]; short8 s; } tt;
        tt.u[0] = Wp[m][c][0][0]; tt.u[1] = Wp[m][c][0][1];
        tt.u[2] = Wp[m][c][1][0]; tt.u[3] = Wp[m][c][1][1];
        pa[m][c] = tt.s;
      }
    // PV: O += P·V
    const short* Vbuf = &Vt[buf][0];
#pragma unroll
    for (int df=0; df<4; ++df){
      int h = (df*2 + (lr >> 3)) & 7;
      int rowv = (df*16 + lr)*72;
      short8 vb0 = *(const short8*)&Vbuf[rowv + ((lg ^ h) << 3)];
      short8 vb1 = *(const short8*)&Vbuf[rowv + (((lg + 4) ^ h) << 3)];
#pragma unroll
      for (int m=0; m<2; ++m){
        o[m][df] = __builtin_amdgcn_mfma_f32_16x16x32_bf16(pa[m][0], vb0, o[m][df], 0, 0, 0);
        o[m][df] = __builtin_amdgcn_mfma_f32_16x16x32_bf16(pa[m][1], vb1, o[m][df], 0, 0, 0);
      }
    }
    if (pre){
#pragma unroll
      for (int j=0; j<8; ++j){
        Vt[nbuf][(d0 + j)*72 + c0] = nv0[j];
        Vt[nbuf][(d0 + j)*72 + c1] = nv1[j];
      }
    }
    __syncthreads();
  }
  // epilogue: reduce lsum across lane groups, normalize, write AO[b][s][h*64+d]
  lsum[0] += __shfl_xor(lsum[0], 16); lsum[0] += __shfl_xor(lsum[0], 32);
  lsum[1] += __shfl_xor(lsum[1], 16); lsum[1] += __shfl_xor(lsum[1], 32);
  int b = bh >> 4, hh = bh & 15;
#pragma unroll
  for (int m=0; m<2; ++m){
    float rinv[4];
#pragma unroll
    for (int i2=0; i2<4; ++i2) rinv[i2] = 1.0f / __shfl(lsum[m], (lg << 2) + i2);
#pragma unroll
    for (int df=0; df<4; ++df)
#pragma unroll
      for (int i2=0; i2<4; ++i2){
        int row = q0 + m*16 + lg*4 + i2;
        int col = df*16 + lr;
        AO[((size_t)(b*2048 + row))*1024 + hh*64 + col] = f2bf(o[m][df][i2] * rinv[i2]);
      }
  }
}

extern "C" void kernel_launch(void* const* d_in, const int* in_sizes, int n_in,
                              void* d_out, int out_size, void* d_ws, size_t ws_size,
                              hipStream_t stream){
  const float* q  = (const float*)d_in[0];
  const float* k  = (const float*)d_in[1];
  const float* v  = (const float*)d_in[2];
  const float* Wq = (const float*)d_in[3];
  const float* bq = (const float*)d_in[4];
  const float* Wk = (const float*)d_in[5];
  const float* bk = (const float*)d_in[6];
  const float* Wv = (const float*)d_in[7];
  const float* bv = (const float*)d_in[8];
  const float* Wo = (const float*)d_in[9];
  const float* bo = (const float*)d_in[10];

  const size_t SQ = 4096ull*1024ull, NW = 1024ull*1024ull;
  short* ws  = (short*)d_ws;
  short* qb  = ws;                    // bf16 q      [4096,1024]
  short* kb  = ws + SQ;
  short* vb  = ws + 2*SQ;
  short* Wqb = ws + 3*SQ;             // bf16 weights [1024,1024]
  short* Wkb = Wqb + NW;
  short* Wvb = Wkb + NW;
  short* Wob = Wvb + NW;
  short* Qh  = Wob + NW;              // [B,H,S,D] bf16
  short* Kh  = Qh + SQ;
  short* Vh  = Kh + SQ;
  short* AO  = qb;                    // reuse q buffer for attention output

  cvt_all<<<8192, 256, 0, stream>>>(q, k, v, Wq, Wk, Wv, Wo, ws);
  gemm_nt<0><<<dim3(16, 32), 256, 0, stream>>>(qb, Wqb, bq, Qh);
  gemm_nt<0><<<dim3(16, 32), 256, 0, stream>>>(kb, Wkb, bk, Kh);
  gemm_nt<0><<<dim3(16, 32), 256, 0, stream>>>(vb, Wvb, bv, Vh);
  attn_fwd<<<dim3(16, 32), 256, 0, stream>>>(Qh, Kh, Vh, AO);
  gemm_nt<1><<<dim3(16, 32), 256, 0, stream>>>(AO, Wob, bo, d_out);
}

// Round 6
// 123.868 us; speedup vs baseline: 1.7789x; 1.2966x over previous
//
#include <hip/hip_runtime.h>
#include <stdint.h>

typedef __attribute__((ext_vector_type(8))) short short8;
typedef __attribute__((ext_vector_type(4))) float f32x4;
typedef __attribute__((ext_vector_type(4))) uint32_t u32x4;

#if __has_builtin(__builtin_amdgcn_exp2f)
#define EXP2(x) __builtin_amdgcn_exp2f(x)
#else
#define EXP2(x) exp2f(x)
#endif

// round-nearest-ties-away bf16: statistically unbiased, 2 VALU ops
__device__ __forceinline__ short f2bf(float f){
  uint32_t u = __builtin_bit_cast(uint32_t, f);
  return (short)((u + 0x8000u) >> 16);
}
// pack two rounded bf16 (lo in low half): 2 adds + 1 v_perm
__device__ __forceinline__ uint32_t pk2(float lo, float hi){
  uint32_t a = __builtin_bit_cast(uint32_t, lo) + 0x8000u;
  uint32_t b = __builtin_bit_cast(uint32_t, hi) + 0x8000u;
#if __has_builtin(__builtin_amdgcn_perm)
  return __builtin_amdgcn_perm(b, a, 0x07060302u);   // [b3 b2 a3 a2]
#else
  return (b & 0xFFFF0000u) | (a >> 16);
#endif
}
__device__ __forceinline__ void gload16(const void* g, void* l){
  __builtin_amdgcn_global_load_lds((const __attribute__((address_space(1))) void*)g,
                                   (__attribute__((address_space(3))) void*)l, 16, 0, 0);
}

// ---------------- fp32 -> bf16 conversion of q,k,v,Wq,Wk,Wv,Wo ----------------
__global__ __launch_bounds__(512) void cvt_all(
    const float* __restrict__ q, const float* __restrict__ k, const float* __restrict__ v,
    const float* __restrict__ wq, const float* __restrict__ wk, const float* __restrict__ wv,
    const float* __restrict__ wo, short* __restrict__ dst){
  const size_t SQ = 4096ull*1024ull, NW = 1024ull*1024ull;
  size_t e = (size_t)(blockIdx.x*512u + threadIdx.x)*8ull;
  const float* src; size_t rel;
  if (e < 3*SQ){ size_t which = e / SQ; src = which==0?q:(which==1?k:v); rel = e - which*SQ; }
  else { size_t e2 = e - 3*SQ; size_t which = e2 / NW;
         src = which==0?wq:(which==1?wk:(which==2?wv:wo)); rel = e2 - which*NW; }
  float4 a = *(const float4*)(src + rel);
  float4 b = *(const float4*)(src + rel + 4);
  u32x4 r = { pk2(a.x,a.y), pk2(a.z,a.w), pk2(b.x,b.y), pk2(b.z,b.w) };
  *(u32x4*)(dst + e) = r;
}

// ---------------- NT GEMM core: 128x64 tile, BK=64, 512 thr, XOR-swizzled LDS ----------------
// LDS[row][chunk] holds A[row][k-chunk (chunk ^ (row&7))]; chunk=16B=8 bf16.
template<int MODE>
__device__ __forceinline__ void gemm_body(const short* __restrict__ A, const short* __restrict__ Bw,
    const float* __restrict__ bias, void* __restrict__ Cout, float scale, int m0, int n0){
  const int K = 1024;
  __shared__ short Al[128*64];
  __shared__ short Bl[64*64];
  int tid = threadIdx.x;
  int w = tid >> 6, lane = tid & 63, lr = lane & 15, lg = lane >> 4;
  int wr = w >> 1, wc = w & 1;
  f32x4 acc[2][2] = {};
  int row0 = tid >> 3;                       // 0..63
  int qc0  = (tid & 7) ^ (row0 & 7);
  const short* Ag = A  + (size_t)(m0 + row0)*K + qc0*8;
  const short* Bg = Bw + (size_t)(n0 + row0)*K + qc0*8;
  char* Alb = (char*)Al + tid*16;
  char* Blb = (char*)Bl + tid*16;
  // read addressing (hoisted)
  int ra[2], rb[2];
#pragma unroll
  for (int mi=0; mi<2; ++mi){ int r = wr*32 + mi*16 + lr; ra[mi] = r; }
#pragma unroll
  for (int ni=0; ni<2; ++ni){ int r = wc*32 + ni*16 + lr; rb[ni] = r; }
  for (int k0 = 0; k0 < K; k0 += 64){
    gload16(Ag + k0,                Alb);
    gload16(Ag + k0 + 64*(size_t)K, Alb + 8192);
    gload16(Bg + k0,                Blb);
    __syncthreads();
#pragma unroll
    for (int kk=0; kk<2; ++kk){
      short8 av[2], bv[2];
#pragma unroll
      for (int mi=0; mi<2; ++mi)
        av[mi] = *(const short8*)((char*)Al + ra[mi]*128 + (((kk*4 + lg) ^ (ra[mi] & 7)) << 4));
#pragma unroll
      for (int ni=0; ni<2; ++ni)
        bv[ni] = *(const short8*)((char*)Bl + rb[ni]*128 + (((kk*4 + lg) ^ (rb[ni] & 7)) << 4));
#pragma unroll
      for (int mi=0; mi<2; ++mi)
#pragma unroll
        for (int ni=0; ni<2; ++ni)
          acc[mi][ni] = __builtin_amdgcn_mfma_f32_16x16x32_bf16(av[mi], bv[ni], acc[mi][ni], 0, 0, 0);
    }
    __syncthreads();
  }
#pragma unroll
  for (int ni=0; ni<2; ++ni){
    int col = n0 + wc*32 + ni*16 + lr;
    float bb = bias[col];
#pragma unroll
    for (int mi=0; mi<2; ++mi){
#pragma unroll
      for (int i2=0; i2<4; ++i2){
        int row = m0 + wr*32 + mi*16 + lg*4 + i2;
        float val = (acc[mi][ni][i2] + bb) * scale;
        if (MODE == 0){
          int b = row >> 11, s = row & 2047, h = col >> 6, d = col & 63;
          ((short*)Cout)[(((size_t)(b*16 + h))*2048 + s)*64 + d] = f2bf(val);
        } else {
          ((float*)Cout)[(size_t)row*1024 + col] = val;
        }
      }
    }
  }
}

// fused q/k/v projections: blockIdx selects (proj, tile) via XCD-bijective remap
__global__ __launch_bounds__(512) void gemm_qkv(
    const short* __restrict__ qb, const short* __restrict__ kb, const short* __restrict__ vb,
    const short* __restrict__ Wqb, const short* __restrict__ Wkb, const short* __restrict__ Wvb,
    const float* __restrict__ bq, const float* __restrict__ bk, const float* __restrict__ bv,
    short* __restrict__ Qh, short* __restrict__ Kh, short* __restrict__ Vh, float qscale){
  int f = (blockIdx.z*32 + blockIdx.y)*16 + blockIdx.x;   // 0..1535
  int L = (f & 7)*192 + (f >> 3);
  int z = L >> 9, r = L & 511;
  int m0 = (r >> 4)*128, n0 = (r & 15)*64;
  const short* A  = z==0 ? qb  : (z==1 ? kb  : vb);
  const short* Bw = z==0 ? Wqb : (z==1 ? Wkb : Wvb);
  const float* bi = z==0 ? bq  : (z==1 ? bk  : bv);
  short* C        = z==0 ? Qh  : (z==1 ? Kh  : Vh);
  float s = z==0 ? qscale : 1.0f;
  gemm_body<0>(A, Bw, bi, (void*)C, s, m0, n0);
}

__global__ __launch_bounds__(512) void gemm_out(const short* __restrict__ A, const short* __restrict__ Bw,
    const float* __restrict__ bias, float* __restrict__ Cout){
  int f = blockIdx.y*gridDim.x + blockIdx.x;
  int L = (f & 7)*64 + (f >> 3);
  int m0 = (L >> 4)*128, n0 = (L & 15)*64;
  gemm_body<1>(A, Bw, bias, (void*)Cout, 1.0f, m0, n0);
}

// ---------------- flash attention: 8 waves x 16 q-rows, register P ----------------
// Swapped QK^T with permuted K-rows: iteration nf covers K rows
// R = 32*(nf>>1) + 8*(lr>>2) + 4*(nf&1) + (lr&3), so lane(lg) accumulates scores for
// k = 32c + 8*lg + 4*(nf&1) + i2 — exactly the PV A-fragment set (P never leaves regs).
// Q is pre-scaled by log2(e)/8 in the projection, so p = exp2(z) directly.
__global__ __launch_bounds__(512) void attn_fwd(const short* __restrict__ Qh, const short* __restrict__ Kh,
    const short* __restrict__ Vh, short* __restrict__ AO){
  const int S = 2048;
  int i = blockIdx.y*gridDim.x + blockIdx.x;   // 512 wgs
  int L = (i & 7)*64 + (i >> 3);
  int bh = L >> 4, qt = L & 15;
  __shared__ short Kl[2][64*64];     // dbuf K; read-slot swizzle, source-side
  __shared__ short Vt[2][64*72];     // dbuf V^T[d][k], col swizzle k ^ (d&56)
  int tid = threadIdx.x, w = tid >> 6, lane = tid & 63, lr = lane & 15, lg = lane >> 4;
  const short* Qb = Qh + (size_t)bh*S*64;
  const short* Kb = Kh + (size_t)bh*S*64;
  const short* Vb = Vh + (size_t)bh*S*64;
  int q0 = qt*128 + w*16;
  short8 aq[2];
#pragma unroll
  for (int h=0; h<2; ++h)
    aq[h] = *(const short8*)&Qb[(size_t)(q0 + lr)*64 + h*32 + lg*8];
  f32x4 o[4] = {};
  float lsum = 0.f;
  // K staging: 1 gload16/thread, LDS dest linear, source column pre-swizzled
  int koff = tid*16;
  int kr = tid >> 3, kc = tid & 7;
  int ksw = (kr & 3) | (((kr >> 3) & 1) << 2);
  int ksrc = kr*64 + ((kc ^ ksw) << 3);
  // K read addressing
  int Rbase = 8*(lr >> 2) + (lr & 3);
  int sR = (lr & 3) | (((lr >> 2) & 1) << 2);
  int slot0 = (lg ^ sR) << 3, slot1 = ((lg + 4) ^ sR) << 3;
  // V staging: 1 short8 load + 8 b16 writes/thread
  int vr = tid >> 3;                 // k-row 0..63
  int d0 = (tid & 7)*8;
  int c0 = vr ^ d0;
  // ---- prologue: stage tile 0 ----
  gload16(Kb + ksrc, (char*)&Kl[0][0] + koff);
  {
    short8 v0 = *(const short8*)&Vb[(size_t)vr*64 + d0];
#pragma unroll
    for (int j=0; j<8; ++j) Vt[0][(d0 + j)*72 + c0] = v0[j];
  }
  __syncthreads();

  for (int t = 0; t < 32; ++t){
    int buf = t & 1, nbuf = buf ^ 1;
    short8 nv;
    bool pre = (t + 1 < 32);
    if (pre){
      gload16(Kb + (size_t)(t + 1)*4096 + ksrc, (char*)&Kl[nbuf][0] + koff);
      nv = *(const short8*)&Vb[(size_t)((t + 1)*64 + vr)*64 + d0];
    }
    // QK^T (swapped, permuted K-rows) + exp2; P accumulates into A-fragment registers
    const short* Kbuf = &Kl[buf][0];
    uint32_t Wp[2][2][2];   // [c][nf0][s]
#pragma unroll
    for (int nf=0; nf<4; ++nf){
      int R = Rbase + (nf & 1)*4 + (nf >> 1)*32;
      short8 ak0 = *(const short8*)&Kbuf[R*64 + slot0];
      short8 ak1 = *(const short8*)&Kbuf[R*64 + slot1];
      f32x4 z = {};
      z = __builtin_amdgcn_mfma_f32_16x16x32_bf16(ak0, aq[0], z, 0, 0, 0);
      z = __builtin_amdgcn_mfma_f32_16x16x32_bf16(ak1, aq[1], z, 0, 0, 0);
      float p0 = EXP2(z[0]), p1 = EXP2(z[1]);
      float p2 = EXP2(z[2]), p3 = EXP2(z[3]);
      lsum += (p0 + p1) + (p2 + p3);
      Wp[nf >> 1][nf & 1][0] = pk2(p0, p1);
      Wp[nf >> 1][nf & 1][1] = pk2(p2, p3);
    }
    short8 pa[2];
#pragma unroll
    for (int c=0; c<2; ++c){
      union { uint32_t u[4]; short8 s; } tt;
      tt.u[0] = Wp[c][0][0]; tt.u[1] = Wp[c][0][1];
      tt.u[2] = Wp[c][1][0]; tt.u[3] = Wp[c][1][1];
      pa[c] = tt.s;
    }
    // PV: O += P·V
    const short* Vbuf = &Vt[buf][0];
#pragma unroll
    for (int df=0; df<4; ++df){
      int h = (df*2 + (lr >> 3)) & 7;
      int rowv = (df*16 + lr)*72;
      short8 vb0 = *(const short8*)&Vbuf[rowv + ((lg ^ h) << 3)];
      short8 vb1 = *(const short8*)&Vbuf[rowv + (((lg + 4) ^ h) << 3)];
      o[df] = __builtin_amdgcn_mfma_f32_16x16x32_bf16(pa[0], vb0, o[df], 0, 0, 0);
      o[df] = __builtin_amdgcn_mfma_f32_16x16x32_bf16(pa[1], vb1, o[df], 0, 0, 0);
    }
    if (pre){
#pragma unroll
      for (int j=0; j<8; ++j) Vt[nbuf][(d0 + j)*72 + c0] = nv[j];
    }
    __syncthreads();
  }
  // epilogue: reduce lsum across k-slice groups, normalize, write AO[b][s][h*64+d]
  lsum += __shfl_xor(lsum, 16); lsum += __shfl_xor(lsum, 32);
  int b = bh >> 4, hh = bh & 15;
  float rinv[4];
#pragma unroll
  for (int i2=0; i2<4; ++i2) rinv[i2] = 1.0f / __shfl(lsum, (lg << 2) + i2);
#pragma unroll
  for (int df=0; df<4; ++df)
#pragma unroll
    for (int i2=0; i2<4; ++i2){
      int row = q0 + lg*4 + i2;
      int col = df*16 + lr;
      AO[((size_t)(b*2048 + row))*1024 + hh*64 + col] = f2bf(o[df][i2] * rinv[i2]);
    }
}

extern "C" void kernel_launch(void* const* d_in, const int* in_sizes, int n_in,
                              void* d_out, int out_size, void* d_ws, size_t ws_size,
                              hipStream_t stream){
  const float* q  = (const float*)d_in[0];
  const float* k  = (const float*)d_in[1];
  const float* v  = (const float*)d_in[2];
  const float* Wq = (const float*)d_in[3];
  const float* bq = (const float*)d_in[4];
  const float* Wk = (const float*)d_in[5];
  const float* bk = (const float*)d_in[6];
  const float* Wv = (const float*)d_in[7];
  const float* bv = (const float*)d_in[8];
  const float* Wo = (const float*)d_in[9];
  const float* bo = (const float*)d_in[10];

  const size_t SQ = 4096ull*1024ull, NW = 1024ull*1024ull;
  short* ws  = (short*)d_ws;
  short* qb  = ws;                    // bf16 q      [4096,1024]
  short* kb  = ws + SQ;
  short* vb  = ws + 2*SQ;
  short* Wqb = ws + 3*SQ;             // bf16 weights [1024,1024]
  short* Wkb = Wqb + NW;
  short* Wvb = Wkb + NW;
  short* Wob = Wvb + NW;
  short* Qh  = Wob + NW;              // [B,H,S,D] bf16 (Q pre-scaled by log2e/8)
  short* Kh  = Qh + SQ;
  short* Vh  = Kh + SQ;
  short* AO  = qb;                    // reuse q buffer for attention output

  const float Csc = 0.18033688011112042f;   // log2(e)/8

  cvt_all<<<4096, 512, 0, stream>>>(q, k, v, Wq, Wk, Wv, Wo, ws);
  gemm_qkv<<<dim3(16, 32, 3), 512, 0, stream>>>(qb, kb, vb, Wqb, Wkb, Wvb, bq, bk, bv, Qh, Kh, Vh, Csc);
  attn_fwd<<<dim3(16, 32), 512, 0, stream>>>(Qh, Kh, Vh, AO);
  gemm_out<<<dim3(16, 32), 512, 0, stream>>>(AO, Wob, bo, (float*)d_out);
}